// Round 15
// baseline (349.197 us; speedup 1.0000x reference)
//
#include <hip/hip_runtime.h>
#include <hip/hip_bf16.h>
#include <math.h>

// ---------------- constants (match reference) ----------------
#define NN 20000
#define EE 400000
#define GG 64
#define VIN 128
#define CONVD 128
#define NETD 256
#define NXD 9
#define EPS_BN 1e-5f
#define NEG_SLOPE 0.2f

typedef short short8 __attribute__((ext_vector_type(8)));
typedef float floatx4 __attribute__((ext_vector_type(4)));

__device__ __forceinline__ float leaky(float v) {
    return v >= 0.f ? v : NEG_SLOPE * v;
}
__device__ __forceinline__ unsigned short f2bf(float f) {
    union { float f; unsigned u; } v; v.f = f;
    unsigned r = v.u + 0x7FFFu + ((v.u >> 16) & 1u);   // RNE
    return (unsigned short)(r >> 16);
}
__device__ __forceinline__ float bf2f(unsigned short u) {
    union { unsigned u; float f; } v; v.u = ((unsigned)u) << 16;
    return v.f;
}
__device__ __forceinline__ unsigned packbf2(float a, float b) {
    return (unsigned)f2bf(a) | ((unsigned)f2bf(b) << 16);
}

// ---------------- pack helper: B (f32 [K,Nn]) -> MFMA B-frag layout (bf16) -------
__device__ __forceinline__ void pack_one(const float* __restrict__ B,
                                         unsigned short* __restrict__ Bp,
                                         int K, int Nn, int idx) {
    int j = idx & 7, lane = (idx >> 3) & 63, t = idx >> 9;
    int KT = K >> 5;
    int kt = t % KT, nt = t / KT;
    int k = kt * 32 + (lane >> 4) * 8 + j;
    int n = nt * 16 + (lane & 15);
    Bp[idx] = f2bf(B[(size_t)k * Nn + n]);
}

// ------ prep: cast x->bf16, pack W1, pack W2, dst histogram, va = W1 . a ---------
__global__ void prep_kernel(const float* __restrict__ x, unsigned short* __restrict__ xb,
                            const float* __restrict__ W1, unsigned short* __restrict__ W1p,
                            const float* __restrict__ W2, unsigned short* __restrict__ W2p,
                            const int* __restrict__ ei, int* __restrict__ deg,
                            const float* __restrict__ a_s1, const float* __restrict__ a_d1,
                            float* __restrict__ va_s, float* __restrict__ va_d) {
    const int CB = (NN * VIN + 255) / 256;     // 10000
    const int PB = (VIN * 512) / 256;          // 256
    const int QB = (512 * 128) / 256;          // 256
    const int HB = (EE + NN + 255) / 256;      // 1642
    int b = blockIdx.x;
    if (b < CB) {
        int i = b * 256 + threadIdx.x;
        if (i < NN * VIN) xb[i] = f2bf(x[i]);
    } else if (b < CB + PB) {
        int i = (b - CB) * 256 + threadIdx.x;
        pack_one(W1, W1p, VIN, 512, i);
    } else if (b < CB + PB + QB) {
        int i = (b - CB - PB) * 256 + threadIdx.x;
        pack_one(W2, W2p, 512, 128, i);
    } else if (b < CB + PB + QB + HB) {
        int e = (b - CB - PB - QB) * 256 + threadIdx.x;
        if (e < EE + NN) {
            int d = (e < EE) ? ei[EE + e] : e - EE;
            atomicAdd(&deg[d], 1);
        }
    } else {
        // va: 1024 outputs; i<512 -> va_s[k*4+h], else va_d
        int i = (b - CB - PB - QB - HB) * 256 + threadIdx.x;
        int sd = i >> 9;
        int k = (i & 511) >> 2, h = i & 3;
        const float* a = (sd ? a_d1 : a_s1) + h * CONVD;
        const float* wrow = W1 + (size_t)k * 512 + h * CONVD;
        float acc = 0.f;
        for (int c = 0; c < CONVD; c++) acc = fmaf(wrow[c], a[c], acc);
        (sd ? va_d : va_s)[(k << 2) + h] = acc;
    }
}

// ---------------- single-block exclusive scan (LDS-staged, u16 degrees) ----------
__global__ __launch_bounds__(1024) void scan_kernel(const int* __restrict__ deg,
                                                    int* __restrict__ rowptr,
                                                    int n, int total) {
    __shared__ unsigned short sdeg[NN];
    __shared__ int ssum[1024];
    int t = threadIdx.x;
    for (int i = t; i < n; i += 1024) sdeg[i] = (unsigned short)deg[i];
    __syncthreads();
    const int CH = (NN + 1023) / 1024;   // 20
    int base = t * CH;
    int s = 0;
    for (int i = 0; i < CH; i++) {
        int idx = base + i;
        if (idx < n) s += sdeg[idx];
    }
    ssum[t] = s;
    __syncthreads();
    for (int off = 1; off < 1024; off <<= 1) {
        int v = (t >= off) ? ssum[t - off] : 0;
        __syncthreads();
        ssum[t] += v;
        __syncthreads();
    }
    int pre = ssum[t] - s;
    for (int i = 0; i < CH; i++) {
        int idx = base + i;
        if (idx < n) { rowptr[idx] = pre; pre += sdeg[idx]; }
    }
    if (t == 0) rowptr[n] = total;
}

// -------- scatter edges to CSR slots + alpha1 (as1/ad1 = xb @ va) combo ----------
__global__ __launch_bounds__(256) void scatter_alpha(const int* __restrict__ ei,
                                                     const int* __restrict__ rowptr,
                                                     int* __restrict__ cursor,
                                                     int* __restrict__ esrc,
                                                     const unsigned short* __restrict__ xb,
                                                     const float* __restrict__ va_s,
                                                     const float* __restrict__ va_d,
                                                     float* __restrict__ as1,
                                                     float* __restrict__ ad1) {
    const int E = EE, Np = NN;
    const int SB = (E + Np + 255) / 256;
    int b = blockIdx.x;
    if (b < SB) {
        int e = b * 256 + threadIdx.x;
        if (e >= E + Np) return;
        int s = (e < E) ? ei[e] : e - E;
        int d = (e < E) ? ei[E + e] : e - E;
        int slot = rowptr[d] + atomicAdd(&cursor[d], 1);
        esrc[slot] = s;
        return;
    }
    int lane = threadIdx.x & 63;
    int n = (b - SB) * 4 + (threadIdx.x >> 6);
    if (n >= NN) return;
    unsigned xv = *(const unsigned*)(xb + (size_t)n * VIN + lane * 2);
    float x0 = bf2f((unsigned short)(xv & 0xffffu));
    float x1 = bf2f((unsigned short)(xv >> 16));
    float4 vs0 = *(const float4*)(va_s + (lane * 2) * 4);
    float4 vs1 = *(const float4*)(va_s + (lane * 2 + 1) * 4);
    float4 vd0 = *(const float4*)(va_d + (lane * 2) * 4);
    float4 vd1 = *(const float4*)(va_d + (lane * 2 + 1) * 4);
    float s0 = fmaf(x0, vs0.x, x1 * vs1.x);
    float s1 = fmaf(x0, vs0.y, x1 * vs1.y);
    float s2 = fmaf(x0, vs0.z, x1 * vs1.z);
    float s3 = fmaf(x0, vs0.w, x1 * vs1.w);
    float d0 = fmaf(x0, vd0.x, x1 * vd1.x);
    float d1 = fmaf(x0, vd0.y, x1 * vd1.y);
    float d2 = fmaf(x0, vd0.z, x1 * vd1.z);
    float d3 = fmaf(x0, vd0.w, x1 * vd1.w);
#pragma unroll
    for (int o = 32; o > 0; o >>= 1) {
        s0 += __shfl_xor(s0, o); s1 += __shfl_xor(s1, o);
        s2 += __shfl_xor(s2, o); s3 += __shfl_xor(s3, o);
        d0 += __shfl_xor(d0, o); d1 += __shfl_xor(d1, o);
        d2 += __shfl_xor(d2, o); d3 += __shfl_xor(d3, o);
    }
    if (lane == 0) {
        *(float4*)(as1 + (size_t)n * 4) = make_float4(s0, s1, s2, s3);
        *(float4*)(ad1 + (size_t)n * 4) = make_float4(d0, d1, d2, d3);
    }
}

// -------- fused softmax + x-space aggregation, H=4 (one wave per node) -----------
__global__ __launch_bounds__(256) void attn_aggr_x4(const int* __restrict__ rowptr,
                                                    const int* __restrict__ esrc,
                                                    const float* __restrict__ as4,
                                                    const float* __restrict__ ad4,
                                                    const unsigned short* __restrict__ xb,
                                                    unsigned short* __restrict__ xagg) {
    __shared__ float4 sp[4][64];
    __shared__ int ssrc[4][64];
    int lane = threadIdx.x & 63;
    int wv = threadIdx.x >> 6;
    int n = blockIdx.x * 4 + wv;          // grid exactly NN/4 blocks
    int beg = rowptr[n], end = rowptr[n + 1];
    int deg = end - beg;
    float4 adn = *(const float4*)(ad4 + (size_t)n * 4);
    float m0, m1, m2, m3, s0, s1, s2, s3;
    if (deg <= 64) {
        bool valid = lane < deg;
        int s = esrc[beg + (valid ? lane : 0)];
        float4 av = *(const float4*)(as4 + (size_t)s * 4);
        float l0 = valid ? leaky(av.x + adn.x) : -INFINITY;
        float l1 = valid ? leaky(av.y + adn.y) : -INFINITY;
        float l2 = valid ? leaky(av.z + adn.z) : -INFINITY;
        float l3 = valid ? leaky(av.w + adn.w) : -INFINITY;
        m0 = l0; m1 = l1; m2 = l2; m3 = l3;
#pragma unroll
        for (int o = 32; o > 0; o >>= 1) {
            m0 = fmaxf(m0, __shfl_xor(m0, o));
            m1 = fmaxf(m1, __shfl_xor(m1, o));
            m2 = fmaxf(m2, __shfl_xor(m2, o));
            m3 = fmaxf(m3, __shfl_xor(m3, o));
        }
        float e0 = valid ? __expf(l0 - m0) : 0.f;
        float e1 = valid ? __expf(l1 - m1) : 0.f;
        float e2 = valid ? __expf(l2 - m2) : 0.f;
        float e3 = valid ? __expf(l3 - m3) : 0.f;
        s0 = e0; s1 = e1; s2 = e2; s3 = e3;
#pragma unroll
        for (int o = 32; o > 0; o >>= 1) {
            s0 += __shfl_xor(s0, o); s1 += __shfl_xor(s1, o);
            s2 += __shfl_xor(s2, o); s3 += __shfl_xor(s3, o);
        }
        sp[wv][lane] = make_float4(e0, e1, e2, e3);
        ssrc[wv][lane] = s;
    } else {
        // rare overflow path: classic two-pass; stash first-64 p in LDS
        m0 = -INFINITY; m1 = -INFINITY; m2 = -INFINITY; m3 = -INFINITY;
        for (int j = beg + lane; j < end; j += 64) {
            float4 av = *(const float4*)(as4 + (size_t)esrc[j] * 4);
            m0 = fmaxf(m0, leaky(av.x + adn.x));
            m1 = fmaxf(m1, leaky(av.y + adn.y));
            m2 = fmaxf(m2, leaky(av.z + adn.z));
            m3 = fmaxf(m3, leaky(av.w + adn.w));
        }
#pragma unroll
        for (int o = 32; o > 0; o >>= 1) {
            m0 = fmaxf(m0, __shfl_xor(m0, o));
            m1 = fmaxf(m1, __shfl_xor(m1, o));
            m2 = fmaxf(m2, __shfl_xor(m2, o));
            m3 = fmaxf(m3, __shfl_xor(m3, o));
        }
        s0 = 0.f; s1 = 0.f; s2 = 0.f; s3 = 0.f;
        for (int j = beg + lane; j < end; j += 64) {
            int s = esrc[j];
            float4 av = *(const float4*)(as4 + (size_t)s * 4);
            float e0 = __expf(leaky(av.x + adn.x) - m0);
            float e1 = __expf(leaky(av.y + adn.y) - m1);
            float e2 = __expf(leaky(av.z + adn.z) - m2);
            float e3 = __expf(leaky(av.w + adn.w) - m3);
            if (j - beg < 64) {
                sp[wv][lane] = make_float4(e0, e1, e2, e3);
                ssrc[wv][lane] = s;
            }
            s0 += e0; s1 += e1; s2 += e2; s3 += e3;
        }
#pragma unroll
        for (int o = 32; o > 0; o >>= 1) {
            s0 += __shfl_xor(s0, o); s1 += __shfl_xor(s1, o);
            s2 += __shfl_xor(s2, o); s3 += __shfl_xor(s3, o);
        }
    }
    __syncthreads();
    float i0 = 1.f / (s0 + 1e-16f), i1 = 1.f / (s1 + 1e-16f);
    float i2 = 1.f / (s2 + 1e-16f), i3 = 1.f / (s3 + 1e-16f);
    // phase C: 8-wide pipelined edge walk (p/src broadcast-read from LDS)
    float a00 = 0.f, a01 = 0.f, a10 = 0.f, a11 = 0.f;
    float a20 = 0.f, a21 = 0.f, a30 = 0.f, a31 = 0.f;
    const unsigned short* xrow = xb + lane * 2;
    int cap = deg < 64 ? deg : 64;
    int jj = 0;
    for (; jj + 7 < cap; jj += 8) {
        int sv[8];
#pragma unroll
        for (int u = 0; u < 8; u++) sv[u] = ssrc[wv][jj + u];
        unsigned xv[8];
#pragma unroll
        for (int u = 0; u < 8; u++) xv[u] = *(const unsigned*)(xrow + (size_t)sv[u] * VIN);
        float4 pv[8];
#pragma unroll
        for (int u = 0; u < 8; u++) pv[u] = sp[wv][jj + u];
#pragma unroll
        for (int u = 0; u < 8; u++) {
            float x0 = bf2f((unsigned short)(xv[u] & 0xffffu));
            float x1 = bf2f((unsigned short)(xv[u] >> 16));
            a00 = fmaf(pv[u].x, x0, a00); a01 = fmaf(pv[u].x, x1, a01);
            a10 = fmaf(pv[u].y, x0, a10); a11 = fmaf(pv[u].y, x1, a11);
            a20 = fmaf(pv[u].z, x0, a20); a21 = fmaf(pv[u].z, x1, a21);
            a30 = fmaf(pv[u].w, x0, a30); a31 = fmaf(pv[u].w, x1, a31);
        }
    }
    for (; jj < cap; jj++) {
        int s = ssrc[wv][jj];
        float4 p = sp[wv][jj];
        unsigned xv = *(const unsigned*)(xrow + (size_t)s * VIN);
        float x0 = bf2f((unsigned short)(xv & 0xffffu));
        float x1 = bf2f((unsigned short)(xv >> 16));
        a00 = fmaf(p.x, x0, a00); a01 = fmaf(p.x, x1, a01);
        a10 = fmaf(p.y, x0, a10); a11 = fmaf(p.y, x1, a11);
        a20 = fmaf(p.z, x0, a20); a21 = fmaf(p.z, x1, a21);
        a30 = fmaf(p.w, x0, a30); a31 = fmaf(p.w, x1, a31);
    }
    for (int j2 = 64; j2 < deg; j2++) {      // rare overflow tail
        int s = esrc[beg + j2];
        float4 av = *(const float4*)(as4 + (size_t)s * 4);
        float p0 = __expf(leaky(av.x + adn.x) - m0);
        float p1 = __expf(leaky(av.y + adn.y) - m1);
        float p2 = __expf(leaky(av.z + adn.z) - m2);
        float p3 = __expf(leaky(av.w + adn.w) - m3);
        unsigned xv = *(const unsigned*)(xrow + (size_t)s * VIN);
        float x0 = bf2f((unsigned short)(xv & 0xffffu));
        float x1 = bf2f((unsigned short)(xv >> 16));
        a00 = fmaf(p0, x0, a00); a01 = fmaf(p0, x1, a01);
        a10 = fmaf(p1, x0, a10); a11 = fmaf(p1, x1, a11);
        a20 = fmaf(p2, x0, a20); a21 = fmaf(p2, x1, a21);
        a30 = fmaf(p3, x0, a30); a31 = fmaf(p3, x1, a31);
    }
    unsigned* obase = (unsigned*)(xagg + (size_t)n * 512 + lane * 2);
    obase[0]   = packbf2(a00 * i0, a01 * i0);
    obase[64]  = packbf2(a10 * i1, a11 * i1);
    obase[128] = packbf2(a20 * i2, a21 * i2);
    obase[192] = packbf2(a30 * i3, a31 * i3);
}

// -------- gemm_agg: out1[n, h*128+c'] = xagg[n,h,:] @ W1[:, h*128+c'] ------------
__global__ __launch_bounds__(256) void gemm_agg(const unsigned short* __restrict__ A,
                                                const unsigned short* __restrict__ Bp,
                                                unsigned short* __restrict__ C,
                                                float* __restrict__ stats, int M) {
    constexpr int KT = 4;            // K = 128
    __shared__ float sred[128];
    __shared__ float qred[128];
    if (threadIdx.x < 128) { sred[threadIdx.x] = 0.f; qred[threadIdx.x] = 0.f; }
    __syncthreads();
    int wave = threadIdx.x >> 6, lane = threadIdx.x & 63;
    int hh = blockIdx.y;
    int row0 = (blockIdx.x * 4 + wave) * 16;
    bool act = row0 < M;
    int rowc = act ? row0 : 0;
    int r = lane & 15, quad = lane >> 4;
    short8 af[KT];
    const unsigned short* arow = A + (size_t)(rowc + r) * 512 + hh * CONVD + quad * 8;
#pragma unroll
    for (int kt = 0; kt < KT; kt++) af[kt] = *(const short8*)(arow + kt * 32);
#pragma unroll
    for (int nt = 0; nt < 8; nt++) {
        floatx4 acc = {0.f, 0.f, 0.f, 0.f};
        const unsigned short* bbase = Bp + (((size_t)(hh * 8 + nt) * KT) << 9) + lane * 8;
#pragma unroll
        for (int kt = 0; kt < KT; kt++) {
            short8 bf = *(const short8*)(bbase + ((size_t)kt << 9));
            acc = __builtin_amdgcn_mfma_f32_16x16x32_bf16(af[kt], bf, acc, 0, 0, 0);
        }
        int col = (hh * 8 + nt) * 16 + r;
        unsigned short* cbase = C + (size_t)(rowc + quad * 4) * 512 + col;
        float ls = 0.f, lq = 0.f;
#pragma unroll
        for (int reg = 0; reg < 4; reg++) {
            float v = acc[reg];
            if (act) cbase[(size_t)reg * 512] = f2bf(v);
            ls += v;
            lq = fmaf(v, v, lq);
        }
        if (!act) { ls = 0.f; lq = 0.f; }
        ls += __shfl_xor(ls, 16); ls += __shfl_xor(ls, 32);
        lq += __shfl_xor(lq, 16); lq += __shfl_xor(lq, 32);
        if (quad == 0) {
            atomicAdd(&sred[nt * 16 + r], ls);
            atomicAdd(&qred[nt * 16 + r], lq);
        }
    }
    __syncthreads();
    if (threadIdx.x < 128) {
        int col = hh * CONVD + threadIdx.x;
        atomicAdd(&stats[col], sred[threadIdx.x]);
        atomicAdd(&stats[512 + col], qred[threadIdx.x]);
    }
}

// ---- GEMM2: BN-finalize in LDS + BN on A-load + fused alpha; N split 4-way ------
__global__ __launch_bounds__(256) void gemm2_bn_alpha(const unsigned short* __restrict__ A,
                                                      const unsigned short* __restrict__ Bp,
                                                      const float* __restrict__ stats,
                                                      const float* __restrict__ gamma,
                                                      const float* __restrict__ beta,
                                                      const float* __restrict__ a_s,
                                                      const float* __restrict__ a_d,
                                                      unsigned short* __restrict__ C,
                                                      float* __restrict__ as_out,
                                                      float* __restrict__ ad_out, int M) {
    constexpr int K = 512;
    constexpr int Nn = CONVD;         // 128
    constexpr int KT = K / 32;        // 16
    __shared__ float Ssm[512];
    __shared__ float Tsm[512];
    for (int c = threadIdx.x; c < 512; c += 256) {
        float inv_n = 1.f / (float)NN;
        float mu = stats[c] * inv_n;
        float var = stats[512 + c] * inv_n - mu * mu;
        float s = gamma[c] * rsqrtf(var + EPS_BN);
        Ssm[c] = s;
        Tsm[c] = fmaf(-mu, s, beta[c]);
    }
    __syncthreads();
    int wave = threadIdx.x >> 6, lane = threadIdx.x & 63;
    int row0 = (blockIdx.x * 4 + wave) * 16;
    if (row0 >= M) return;
    int r = lane & 15, quad = lane >> 4;
    int nt0 = blockIdx.y * 2;
    short8 af[KT];
    const unsigned short* arow = A + (size_t)(row0 + r) * K + quad * 8;
#pragma unroll
    for (int kt = 0; kt < KT; kt++) {
        short8 raw = *(const short8*)(arow + kt * 32);
        int k = kt * 32 + quad * 8;
        short8 o;
#pragma unroll
        for (int i = 0; i < 8; i++) {
            float v = fmaf(bf2f((unsigned short)raw[i]), Ssm[k + i], Tsm[k + i]);
            o[i] = (short)f2bf(v > 0.f ? v : 0.f);
        }
        af[kt] = o;
    }
    float asp[4] = {}, adp[4] = {};
#pragma unroll
    for (int nt2 = 0; nt2 < 2; nt2++) {
        int nt = nt0 + nt2;
        floatx4 acc = {0.f, 0.f, 0.f, 0.f};
        const unsigned short* bbase = Bp + (((size_t)nt * KT) << 9) + lane * 8;
#pragma unroll
        for (int kt = 0; kt < KT; kt++) {
            short8 bf = *(const short8*)(bbase + ((size_t)kt << 9));
            acc = __builtin_amdgcn_mfma_f32_16x16x32_bf16(af[kt], bf, acc, 0, 0, 0);
        }
        int col = nt * 16 + r;
        unsigned short* cbase = C + (size_t)(row0 + quad * 4) * Nn + col;
        float sv = a_s[col];
        float dv = a_d[col];
#pragma unroll
        for (int reg = 0; reg < 4; reg++) {
            cbase[(size_t)reg * Nn] = f2bf(acc[reg]);
            asp[reg] = fmaf(acc[reg], sv, asp[reg]);
            adp[reg] = fmaf(acc[reg], dv, adp[reg]);
        }
    }
#pragma unroll
    for (int msk = 1; msk < 16; msk <<= 1) {
#pragma unroll
        for (int reg = 0; reg < 4; reg++) {
            asp[reg] += __shfl_xor(asp[reg], msk);
            adp[reg] += __shfl_xor(adp[reg], msk);
        }
    }
    if (r < 4) {
        int row = row0 + quad * 4 + r;
        atomicAdd(&as_out[row], asp[r]);
        atomicAdd(&ad_out[row], adp[r]);
    }
}

// -------- fused softmax + aggregation, H=1 (one wave per node), LDS + 8-wide -----
__global__ __launch_bounds__(256) void attn_aggr1(const int* __restrict__ rowptr,
                                                  const int* __restrict__ esrc,
                                                  const float* __restrict__ as,
                                                  const float* __restrict__ ad,
                                                  const unsigned short* __restrict__ h,
                                                  float* __restrict__ out) {
    __shared__ float sp[4][64];
    __shared__ int ssrc[4][64];
    int lane = threadIdx.x & 63;
    int wv = threadIdx.x >> 6;
    int n = blockIdx.x * 4 + wv;
    int beg = rowptr[n], end = rowptr[n + 1];
    int deg = end - beg;
    float adn = ad[n];
    float m, sum;
    if (deg <= 64) {
        bool valid = lane < deg;
        int s = esrc[beg + (valid ? lane : 0)];
        float l = valid ? leaky(as[s] + adn) : -INFINITY;
        m = l;
#pragma unroll
        for (int o = 32; o > 0; o >>= 1) m = fmaxf(m, __shfl_xor(m, o));
        float e = valid ? __expf(l - m) : 0.f;
        sum = e;
#pragma unroll
        for (int o = 32; o > 0; o >>= 1) sum += __shfl_xor(sum, o);
        sp[wv][lane] = e;
        ssrc[wv][lane] = s;
    } else {
        m = -INFINITY;
        for (int j = beg + lane; j < end; j += 64)
            m = fmaxf(m, leaky(as[esrc[j]] + adn));
#pragma unroll
        for (int o = 32; o > 0; o >>= 1) m = fmaxf(m, __shfl_xor(m, o));
        sum = 0.f;
        for (int j = beg + lane; j < end; j += 64) {
            int s = esrc[j];
            float e = __expf(leaky(as[s] + adn) - m);
            if (j - beg < 64) { sp[wv][lane] = e; ssrc[wv][lane] = s; }
            sum += e;
        }
#pragma unroll
        for (int o = 32; o > 0; o >>= 1) sum += __shfl_xor(sum, o);
    }
    __syncthreads();
    float inv = 1.f / (sum + 1e-16f);
    float a0 = 0.f, a1 = 0.f;
    const unsigned short* hrow = h + lane * 2;
    int cap = deg < 64 ? deg : 64;
    int jj = 0;
    for (; jj + 7 < cap; jj += 8) {
        int sv[8];
#pragma unroll
        for (int u = 0; u < 8; u++) sv[u] = ssrc[wv][jj + u];
        unsigned xv[8];
#pragma unroll
        for (int u = 0; u < 8; u++) xv[u] = *(const unsigned*)(hrow + (size_t)sv[u] * CONVD);
        float pv[8];
#pragma unroll
        for (int u = 0; u < 8; u++) pv[u] = sp[wv][jj + u];
#pragma unroll
        for (int u = 0; u < 8; u++) {
            a0 = fmaf(pv[u], bf2f((unsigned short)(xv[u] & 0xffffu)), a0);
            a1 = fmaf(pv[u], bf2f((unsigned short)(xv[u] >> 16)), a1);
        }
    }
    for (; jj < cap; jj++) {
        int s = ssrc[wv][jj];
        float p = sp[wv][jj];
        unsigned xv = *(const unsigned*)(hrow + (size_t)s * CONVD);
        a0 = fmaf(p, bf2f((unsigned short)(xv & 0xffffu)), a0);
        a1 = fmaf(p, bf2f((unsigned short)(xv >> 16)), a1);
    }
    for (int j2 = 64; j2 < deg; j2++) {
        int s = esrc[beg + j2];
        float p = __expf(leaky(as[s] + adn) - m);
        unsigned xv = *(const unsigned*)(hrow + (size_t)s * CONVD);
        a0 = fmaf(p, bf2f((unsigned short)(xv & 0xffffu)), a0);
        a1 = fmaf(p, bf2f((unsigned short)(xv >> 16)), a1);
    }
    *(float2*)(out + (size_t)n * CONVD + lane * 2) = make_float2(a0 * inv, a1 * inv);
}

// ---------------- BN stats (f32 input) ----------------
__global__ void bn_stats_f32(const float* __restrict__ x, const float* __restrict__ bias,
                             float* __restrict__ stats, int Nn, int C) {
    const int ROWS = 64;
    int r0 = blockIdx.x * ROWS;
    int rend = min(r0 + ROWS, Nn);
    for (int c = threadIdx.x; c < C; c += blockDim.x) {
        float b = bias[c];
        float s1 = 0.f, s2 = 0.f;
        for (int r = r0; r < rend; r++) {
            float v = x[(size_t)r * C + c] + b;
            s1 += v;
            s2 = fmaf(v, v, s2);
        }
        atomicAdd(&stats[c], s1);
        atomicAdd(&stats[C + c], s2);
    }
}

// ---------------- BN apply + ReLU + pool (layer 2, fused) ------------------------
__global__ void bn_apply_pool(const float* __restrict__ x, const float* __restrict__ bias,
                              const float* __restrict__ stats,
                              const float* __restrict__ gamma, const float* __restrict__ beta,
                              const int* __restrict__ batch, float* __restrict__ z,
                              int Nn, int C) {
    int idx = blockIdx.x * blockDim.x + threadIdx.x;
    if (idx >= Nn * C) return;
    int c = idx % C;
    int n = idx / C;
    float inv_n = 1.f / (float)Nn;
    float mu = stats[c] * inv_n;
    float var = stats[C + c] * inv_n - mu * mu;
    float v = (x[idx] + bias[c] - mu) * rsqrtf(var + EPS_BN);
    v = fmaf(gamma[c], v, beta[c]);
    v = v > 0.f ? v : 0.f;
    atomicAdd(&z[batch[n] * C + c], v);
}

// ---- fused MLP head: one block per graph, 1024 threads, 4-way k-split -----------
// The harness's 256 MiB ws re-poison flushes L2 every iteration, so the ~420 KB of
// MLP weights are cold-HBM reads; k-split gives each thread ~34 independent loads
// in flight and 16 waves/block for latency hiding.
__global__ __launch_bounds__(1024) void mlp_kernel(const float* __restrict__ g,
                           const float* __restrict__ extras,
                           const float* __restrict__ Wm1, const float* __restrict__ bm1,
                           const float* __restrict__ Wm2, const float* __restrict__ bm2,
                           const float* __restrict__ Wm3, const float* __restrict__ bm3,
                           float* __restrict__ out) {
    const int Z0 = CONVD + NXD;   // 137
    const int Z1 = NETD + NXD;    // 265
    const int Z2 = NETD;          // 256
    __shared__ float z[Z0];
    __shared__ float z1[Z1];
    __shared__ float z2[Z2];
    __shared__ float wred[4];
    int gi = blockIdx.x, tid = threadIdx.x;
    if (tid < CONVD) z[tid] = g[gi * CONVD + tid];
    else if (tid < Z0) z[tid] = extras[gi * NXD + (tid - CONVD)];
    __syncthreads();
    int t = tid >> 2, kc = tid & 3;   // t in 0..255, kc in 0..3
    // ---- layer 1: z1[t] = relu(bm1[t] + sum_k z[k] * Wm1[k*Z1+t]) ----
    for (int tt = t; tt < Z1; tt += 256) {
        float acc = 0.f;
        for (int k = kc; k < Z0; k += 4)
            acc = fmaf(z[k], Wm1[(size_t)k * Z1 + tt], acc);
        acc += __shfl_down(acc, 2, 4);
        acc += __shfl_down(acc, 1, 4);
        if (kc == 0) {
            float v = acc + bm1[tt];
            z1[tt] = v > 0.f ? v : 0.f;
        }
    }
    __syncthreads();
    // ---- layer 2: z2[t] = relu(bm2[t] + sum_k z1[k] * Wm2[k*Z2+t]) ----
    {
        float acc = 0.f;
        for (int k = kc; k < Z1; k += 4)
            acc = fmaf(z1[k], Wm2[(size_t)k * Z2 + t], acc);
        acc += __shfl_down(acc, 2, 4);
        acc += __shfl_down(acc, 1, 4);
        if (kc == 0) {
            float v = acc + bm2[t];
            z2[t] = v > 0.f ? v : 0.f;
        }
    }
    __syncthreads();
    // ---- layer 3: out[gi] = bm3 + z2 . Wm3 (first 256 threads = 4 waves) ----
    if (tid < 256) {
        float partial = z2[tid] * Wm3[tid];
        for (int o = 32; o > 0; o >>= 1) partial += __shfl_down(partial, o);
        int wv = tid >> 6, ln = tid & 63;
        if (ln == 0) wred[wv] = partial;
    }
    __syncthreads();
    if (tid == 0) {
        float s = bm3[0];
        for (int i = 0; i < 4; i++) s += wred[i];
        out[gi] = s;
    }
}

// ---------------- launch ----------------
extern "C" void kernel_launch(void* const* d_in, const int* in_sizes, int n_in,
                              void* d_out, int out_size, void* d_ws, size_t ws_size,
                              hipStream_t stream) {
    const float* x      = (const float*)d_in[0];
    const int*   ei     = (const int*)d_in[1];
    const int*   batch  = (const int*)d_in[2];
    const float* extras = (const float*)d_in[3];
    const float* W1     = (const float*)d_in[4];
    const float* a_s1   = (const float*)d_in[5];
    const float* a_d1   = (const float*)d_in[6];
    const float* b1     = (const float*)d_in[7];
    const float* W2     = (const float*)d_in[8];
    const float* a_s2   = (const float*)d_in[9];
    const float* a_d2   = (const float*)d_in[10];
    const float* b2     = (const float*)d_in[11];
    const float* gamma1 = (const float*)d_in[12];
    const float* beta1  = (const float*)d_in[13];
    const float* gamma2 = (const float*)d_in[14];
    const float* beta2  = (const float*)d_in[15];
    const float* Wm1    = (const float*)d_in[16];
    const float* bm1    = (const float*)d_in[17];
    const float* Wm2    = (const float*)d_in[18];
    const float* bm2    = (const float*)d_in[19];
    const float* Wm3    = (const float*)d_in[20];
    const float* bm3    = (const float*)d_in[21];
    float* out = (float*)d_out;

    const int N = NN, E = EE, EP = EE + NN;

    char* ws = (char*)d_ws;
    size_t off = 0;
    auto alloc = [&](size_t bytes) -> void* {
        void* pp = (void*)(ws + off);
        off += (bytes + 255) & ~(size_t)255;
        return pp;
    };
    // --- zero region (contiguous; one small memset) ---
    int*   deg    = (int*)alloc((size_t)N * 4);
    int*   cursor = (int*)alloc((size_t)N * 4);
    float* stats1 = (float*)alloc(512 * 2 * 4);
    float* stats2 = (float*)alloc(128 * 2 * 4);
    float* zbuf   = (float*)alloc((size_t)GG * CONVD * 4);
    float* as2    = (float*)alloc((size_t)N * 4);      // atomic-accumulated in gemm2
    float* ad2    = (float*)alloc((size_t)N * 4);
    size_t zero_bytes = off;
    // --- scratch (fully overwritten each launch) ---
    int*   rowptr = (int*)alloc((size_t)(N + 1) * 4);
    int*   esrc   = (int*)alloc((size_t)EP * 4);
    unsigned short* xb    = (unsigned short*)alloc((size_t)N * VIN * 2);
    unsigned short* W1p   = (unsigned short*)alloc((size_t)VIN * 512 * 2);
    unsigned short* W2p   = (unsigned short*)alloc((size_t)512 * 128 * 2);
    unsigned short* xagg  = (unsigned short*)alloc((size_t)N * 512 * 2);
    unsigned short* out1b = (unsigned short*)alloc((size_t)N * 512 * 2);
    unsigned short* h2b   = (unsigned short*)alloc((size_t)N * 128 * 2);
    float* out2   = (float*)alloc((size_t)N * 128 * 4);
    float* as1    = (float*)alloc((size_t)N * 4 * 4);
    float* ad1    = (float*)alloc((size_t)N * 4 * 4);
    float* va_s   = (float*)alloc(VIN * 4 * 4);
    float* va_d   = (float*)alloc(VIN * 4 * 4);

    hipMemsetAsync(d_ws, 0, zero_bytes, stream);

    int eb = (EP + 255) / 256;                 // 1642
    int nrow = (N + 63) / 64;                  // 313
    int mblk = (N + 63) / 64;                  // 313
    int nblk4 = N / 4;                         // 5000 (exact)
    int prep_blocks = (N * VIN + 255) / 256 + 256 + 256 + eb + 4;
    int sa_blocks = eb + nblk4;

    // ---- prep (cast + packs + histogram + va) ----
    prep_kernel<<<prep_blocks, 256, 0, stream>>>(x, xb, W1, W1p, W2, W2p, ei, deg,
                                                 a_s1, a_d1, va_s, va_d);

    // ---- CSR build + alpha1 ----
    scan_kernel<<<1, 1024, 0, stream>>>(deg, rowptr, N, EP);
    scatter_alpha<<<sa_blocks, 256, 0, stream>>>(ei, rowptr, cursor, esrc, xb, va_s, va_d, as1, ad1);

    // ---- GAT layer 1 (H=4, concat): x-space aggregation then per-head GEMM ----
    attn_aggr_x4<<<nblk4, 256, 0, stream>>>(rowptr, esrc, as1, ad1, xb, xagg);
    gemm_agg<<<dim3(mblk, 4), 256, 0, stream>>>(xagg, W1p, out1b, stats1, N);

    // ---- GAT layer 2 (H=1): BN finalize folded into GEMM2; N split 4-way ----
    gemm2_bn_alpha<<<dim3(mblk, 4), 256, 0, stream>>>(out1b, W2p, stats1, gamma1, beta1,
                                                      a_s2, a_d2, h2b, as2, ad2, N);
    attn_aggr1<<<nblk4, 256, 0, stream>>>(rowptr, esrc, as2, ad2, h2b, out2);

    // ---- tail: BN2 stats -> apply+pool -> MLP (separate small kernels) ----
    bn_stats_f32<<<nrow, 256, 0, stream>>>(out2, b2, stats2, N, 128);
    bn_apply_pool<<<(N * 128 + 255) / 256, 256, 0, stream>>>(out2, b2, stats2, gamma2, beta2, batch, zbuf, N, 128);
    mlp_kernel<<<GG, 1024, 0, stream>>>(zbuf, extras, Wm1, bm1, Wm2, bm2, Wm3, bm3, out);
}

// Round 16
// 333.963 us; speedup vs baseline: 1.0456x; 1.0456x over previous
//
#include <hip/hip_runtime.h>
#include <hip/hip_bf16.h>
#include <math.h>

// ---------------- constants (match reference) ----------------
#define NN 20000
#define EE 400000
#define GG 64
#define VIN 128
#define CONVD 128
#define NETD 256
#define NXD 9
#define EPS_BN 1e-5f
#define NEG_SLOPE 0.2f

typedef short short8 __attribute__((ext_vector_type(8)));
typedef float floatx4 __attribute__((ext_vector_type(4)));

__device__ __forceinline__ float leaky(float v) {
    return v >= 0.f ? v : NEG_SLOPE * v;
}
__device__ __forceinline__ unsigned short f2bf(float f) {
    union { float f; unsigned u; } v; v.f = f;
    unsigned r = v.u + 0x7FFFu + ((v.u >> 16) & 1u);   // RNE
    return (unsigned short)(r >> 16);
}
__device__ __forceinline__ float bf2f(unsigned short u) {
    union { unsigned u; float f; } v; v.u = ((unsigned)u) << 16;
    return v.f;
}
__device__ __forceinline__ unsigned packbf2(float a, float b) {
    return (unsigned)f2bf(a) | ((unsigned)f2bf(b) << 16);
}

// ---------------- pack helper: B (f32 [K,Nn]) -> MFMA B-frag layout (bf16) -------
__device__ __forceinline__ void pack_one(const float* __restrict__ B,
                                         unsigned short* __restrict__ Bp,
                                         int K, int Nn, int idx) {
    int j = idx & 7, lane = (idx >> 3) & 63, t = idx >> 9;
    int KT = K >> 5;
    int kt = t % KT, nt = t / KT;
    int k = kt * 32 + (lane >> 4) * 8 + j;
    int n = nt * 16 + (lane & 15);
    Bp[idx] = f2bf(B[(size_t)k * Nn + n]);
}

// ------ prep: cast x->bf16, pack W1, pack W2, dst histogram, va = W1 . a ---------
__global__ void prep_kernel(const float* __restrict__ x, unsigned short* __restrict__ xb,
                            const float* __restrict__ W1, unsigned short* __restrict__ W1p,
                            const float* __restrict__ W2, unsigned short* __restrict__ W2p,
                            const int* __restrict__ ei, int* __restrict__ deg,
                            const float* __restrict__ a_s1, const float* __restrict__ a_d1,
                            float* __restrict__ va_s, float* __restrict__ va_d) {
    const int CB = (NN * VIN + 255) / 256;     // 10000
    const int PB = (VIN * 512) / 256;          // 256
    const int QB = (512 * 128) / 256;          // 256
    const int HB = (EE + NN + 255) / 256;      // 1642
    int b = blockIdx.x;
    if (b < CB) {
        int i = b * 256 + threadIdx.x;
        if (i < NN * VIN) xb[i] = f2bf(x[i]);
    } else if (b < CB + PB) {
        int i = (b - CB) * 256 + threadIdx.x;
        pack_one(W1, W1p, VIN, 512, i);
    } else if (b < CB + PB + QB) {
        int i = (b - CB - PB) * 256 + threadIdx.x;
        pack_one(W2, W2p, 512, 128, i);
    } else if (b < CB + PB + QB + HB) {
        int e = (b - CB - PB - QB) * 256 + threadIdx.x;
        if (e < EE + NN) {
            int d = (e < EE) ? ei[EE + e] : e - EE;
            atomicAdd(&deg[d], 1);
        }
    } else {
        // va: 1024 outputs; i<512 -> va_s[k*4+h], else va_d
        int i = (b - CB - PB - QB - HB) * 256 + threadIdx.x;
        int sd = i >> 9;
        int k = (i & 511) >> 2, h = i & 3;
        const float* a = (sd ? a_d1 : a_s1) + h * CONVD;
        const float* wrow = W1 + (size_t)k * 512 + h * CONVD;
        float acc = 0.f;
        for (int c = 0; c < CONVD; c++) acc = fmaf(wrow[c], a[c], acc);
        (sd ? va_d : va_s)[(k << 2) + h] = acc;
    }
}

// ---------------- single-block exclusive scan (LDS-staged, u16 degrees) ----------
__global__ __launch_bounds__(1024) void scan_kernel(const int* __restrict__ deg,
                                                    int* __restrict__ rowptr,
                                                    int n, int total) {
    __shared__ unsigned short sdeg[NN];
    __shared__ int ssum[1024];
    int t = threadIdx.x;
    for (int i = t; i < n; i += 1024) sdeg[i] = (unsigned short)deg[i];
    __syncthreads();
    const int CH = (NN + 1023) / 1024;   // 20
    int base = t * CH;
    int s = 0;
    for (int i = 0; i < CH; i++) {
        int idx = base + i;
        if (idx < n) s += sdeg[idx];
    }
    ssum[t] = s;
    __syncthreads();
    for (int off = 1; off < 1024; off <<= 1) {
        int v = (t >= off) ? ssum[t - off] : 0;
        __syncthreads();
        ssum[t] += v;
        __syncthreads();
    }
    int pre = ssum[t] - s;
    for (int i = 0; i < CH; i++) {
        int idx = base + i;
        if (idx < n) { rowptr[idx] = pre; pre += sdeg[idx]; }
    }
    if (t == 0) rowptr[n] = total;
}

// -------- scatter edges to CSR slots + alpha1 (as1/ad1 = xb @ va) combo ----------
__global__ __launch_bounds__(256) void scatter_alpha(const int* __restrict__ ei,
                                                     const int* __restrict__ rowptr,
                                                     int* __restrict__ cursor,
                                                     int* __restrict__ esrc,
                                                     const unsigned short* __restrict__ xb,
                                                     const float* __restrict__ va_s,
                                                     const float* __restrict__ va_d,
                                                     float* __restrict__ as1,
                                                     float* __restrict__ ad1) {
    const int E = EE, Np = NN;
    const int SB = (E + Np + 255) / 256;
    int b = blockIdx.x;
    if (b < SB) {
        int e = b * 256 + threadIdx.x;
        if (e >= E + Np) return;
        int s = (e < E) ? ei[e] : e - E;
        int d = (e < E) ? ei[E + e] : e - E;
        int slot = rowptr[d] + atomicAdd(&cursor[d], 1);
        esrc[slot] = s;
        return;
    }
    int lane = threadIdx.x & 63;
    int n = (b - SB) * 4 + (threadIdx.x >> 6);
    if (n >= NN) return;
    unsigned xv = *(const unsigned*)(xb + (size_t)n * VIN + lane * 2);
    float x0 = bf2f((unsigned short)(xv & 0xffffu));
    float x1 = bf2f((unsigned short)(xv >> 16));
    float4 vs0 = *(const float4*)(va_s + (lane * 2) * 4);
    float4 vs1 = *(const float4*)(va_s + (lane * 2 + 1) * 4);
    float4 vd0 = *(const float4*)(va_d + (lane * 2) * 4);
    float4 vd1 = *(const float4*)(va_d + (lane * 2 + 1) * 4);
    float s0 = fmaf(x0, vs0.x, x1 * vs1.x);
    float s1 = fmaf(x0, vs0.y, x1 * vs1.y);
    float s2 = fmaf(x0, vs0.z, x1 * vs1.z);
    float s3 = fmaf(x0, vs0.w, x1 * vs1.w);
    float d0 = fmaf(x0, vd0.x, x1 * vd1.x);
    float d1 = fmaf(x0, vd0.y, x1 * vd1.y);
    float d2 = fmaf(x0, vd0.z, x1 * vd1.z);
    float d3 = fmaf(x0, vd0.w, x1 * vd1.w);
#pragma unroll
    for (int o = 32; o > 0; o >>= 1) {
        s0 += __shfl_xor(s0, o); s1 += __shfl_xor(s1, o);
        s2 += __shfl_xor(s2, o); s3 += __shfl_xor(s3, o);
        d0 += __shfl_xor(d0, o); d1 += __shfl_xor(d1, o);
        d2 += __shfl_xor(d2, o); d3 += __shfl_xor(d3, o);
    }
    if (lane == 0) {
        *(float4*)(as1 + (size_t)n * 4) = make_float4(s0, s1, s2, s3);
        *(float4*)(ad1 + (size_t)n * 4) = make_float4(d0, d1, d2, d3);
    }
}

// -------- fused softmax + x-space aggregation, H=4 (one wave per node) -----------
__global__ __launch_bounds__(256) void attn_aggr_x4(const int* __restrict__ rowptr,
                                                    const int* __restrict__ esrc,
                                                    const float* __restrict__ as4,
                                                    const float* __restrict__ ad4,
                                                    const unsigned short* __restrict__ xb,
                                                    unsigned short* __restrict__ xagg) {
    __shared__ float4 sp[4][64];
    __shared__ int ssrc[4][64];
    int lane = threadIdx.x & 63;
    int wv = threadIdx.x >> 6;
    int n = blockIdx.x * 4 + wv;          // grid exactly NN/4 blocks
    int beg = rowptr[n], end = rowptr[n + 1];
    int deg = end - beg;
    float4 adn = *(const float4*)(ad4 + (size_t)n * 4);
    float m0, m1, m2, m3, s0, s1, s2, s3;
    if (deg <= 64) {
        bool valid = lane < deg;
        int s = esrc[beg + (valid ? lane : 0)];
        float4 av = *(const float4*)(as4 + (size_t)s * 4);
        float l0 = valid ? leaky(av.x + adn.x) : -INFINITY;
        float l1 = valid ? leaky(av.y + adn.y) : -INFINITY;
        float l2 = valid ? leaky(av.z + adn.z) : -INFINITY;
        float l3 = valid ? leaky(av.w + adn.w) : -INFINITY;
        m0 = l0; m1 = l1; m2 = l2; m3 = l3;
#pragma unroll
        for (int o = 32; o > 0; o >>= 1) {
            m0 = fmaxf(m0, __shfl_xor(m0, o));
            m1 = fmaxf(m1, __shfl_xor(m1, o));
            m2 = fmaxf(m2, __shfl_xor(m2, o));
            m3 = fmaxf(m3, __shfl_xor(m3, o));
        }
        float e0 = valid ? __expf(l0 - m0) : 0.f;
        float e1 = valid ? __expf(l1 - m1) : 0.f;
        float e2 = valid ? __expf(l2 - m2) : 0.f;
        float e3 = valid ? __expf(l3 - m3) : 0.f;
        s0 = e0; s1 = e1; s2 = e2; s3 = e3;
#pragma unroll
        for (int o = 32; o > 0; o >>= 1) {
            s0 += __shfl_xor(s0, o); s1 += __shfl_xor(s1, o);
            s2 += __shfl_xor(s2, o); s3 += __shfl_xor(s3, o);
        }
        sp[wv][lane] = make_float4(e0, e1, e2, e3);
        ssrc[wv][lane] = s;
    } else {
        // rare overflow path: classic two-pass; stash first-64 p in LDS
        m0 = -INFINITY; m1 = -INFINITY; m2 = -INFINITY; m3 = -INFINITY;
        for (int j = beg + lane; j < end; j += 64) {
            float4 av = *(const float4*)(as4 + (size_t)esrc[j] * 4);
            m0 = fmaxf(m0, leaky(av.x + adn.x));
            m1 = fmaxf(m1, leaky(av.y + adn.y));
            m2 = fmaxf(m2, leaky(av.z + adn.z));
            m3 = fmaxf(m3, leaky(av.w + adn.w));
        }
#pragma unroll
        for (int o = 32; o > 0; o >>= 1) {
            m0 = fmaxf(m0, __shfl_xor(m0, o));
            m1 = fmaxf(m1, __shfl_xor(m1, o));
            m2 = fmaxf(m2, __shfl_xor(m2, o));
            m3 = fmaxf(m3, __shfl_xor(m3, o));
        }
        s0 = 0.f; s1 = 0.f; s2 = 0.f; s3 = 0.f;
        for (int j = beg + lane; j < end; j += 64) {
            int s = esrc[j];
            float4 av = *(const float4*)(as4 + (size_t)s * 4);
            float e0 = __expf(leaky(av.x + adn.x) - m0);
            float e1 = __expf(leaky(av.y + adn.y) - m1);
            float e2 = __expf(leaky(av.z + adn.z) - m2);
            float e3 = __expf(leaky(av.w + adn.w) - m3);
            if (j - beg < 64) {
                sp[wv][lane] = make_float4(e0, e1, e2, e3);
                ssrc[wv][lane] = s;
            }
            s0 += e0; s1 += e1; s2 += e2; s3 += e3;
        }
#pragma unroll
        for (int o = 32; o > 0; o >>= 1) {
            s0 += __shfl_xor(s0, o); s1 += __shfl_xor(s1, o);
            s2 += __shfl_xor(s2, o); s3 += __shfl_xor(s3, o);
        }
    }
    __syncthreads();
    float i0 = 1.f / (s0 + 1e-16f), i1 = 1.f / (s1 + 1e-16f);
    float i2 = 1.f / (s2 + 1e-16f), i3 = 1.f / (s3 + 1e-16f);
    // phase C: 8-wide pipelined edge walk (p/src broadcast-read from LDS)
    float a00 = 0.f, a01 = 0.f, a10 = 0.f, a11 = 0.f;
    float a20 = 0.f, a21 = 0.f, a30 = 0.f, a31 = 0.f;
    const unsigned short* xrow = xb + lane * 2;
    int cap = deg < 64 ? deg : 64;
    int jj = 0;
    for (; jj + 7 < cap; jj += 8) {
        int sv[8];
#pragma unroll
        for (int u = 0; u < 8; u++) sv[u] = ssrc[wv][jj + u];
        unsigned xv[8];
#pragma unroll
        for (int u = 0; u < 8; u++) xv[u] = *(const unsigned*)(xrow + (size_t)sv[u] * VIN);
        float4 pv[8];
#pragma unroll
        for (int u = 0; u < 8; u++) pv[u] = sp[wv][jj + u];
#pragma unroll
        for (int u = 0; u < 8; u++) {
            float x0 = bf2f((unsigned short)(xv[u] & 0xffffu));
            float x1 = bf2f((unsigned short)(xv[u] >> 16));
            a00 = fmaf(pv[u].x, x0, a00); a01 = fmaf(pv[u].x, x1, a01);
            a10 = fmaf(pv[u].y, x0, a10); a11 = fmaf(pv[u].y, x1, a11);
            a20 = fmaf(pv[u].z, x0, a20); a21 = fmaf(pv[u].z, x1, a21);
            a30 = fmaf(pv[u].w, x0, a30); a31 = fmaf(pv[u].w, x1, a31);
        }
    }
    for (; jj < cap; jj++) {
        int s = ssrc[wv][jj];
        float4 p = sp[wv][jj];
        unsigned xv = *(const unsigned*)(xrow + (size_t)s * VIN);
        float x0 = bf2f((unsigned short)(xv & 0xffffu));
        float x1 = bf2f((unsigned short)(xv >> 16));
        a00 = fmaf(p.x, x0, a00); a01 = fmaf(p.x, x1, a01);
        a10 = fmaf(p.y, x0, a10); a11 = fmaf(p.y, x1, a11);
        a20 = fmaf(p.z, x0, a20); a21 = fmaf(p.z, x1, a21);
        a30 = fmaf(p.w, x0, a30); a31 = fmaf(p.w, x1, a31);
    }
    for (int j2 = 64; j2 < deg; j2++) {      // rare overflow tail
        int s = esrc[beg + j2];
        float4 av = *(const float4*)(as4 + (size_t)s * 4);
        float p0 = __expf(leaky(av.x + adn.x) - m0);
        float p1 = __expf(leaky(av.y + adn.y) - m1);
        float p2 = __expf(leaky(av.z + adn.z) - m2);
        float p3 = __expf(leaky(av.w + adn.w) - m3);
        unsigned xv = *(const unsigned*)(xrow + (size_t)s * VIN);
        float x0 = bf2f((unsigned short)(xv & 0xffffu));
        float x1 = bf2f((unsigned short)(xv >> 16));
        a00 = fmaf(p0, x0, a00); a01 = fmaf(p0, x1, a01);
        a10 = fmaf(p1, x0, a10); a11 = fmaf(p1, x1, a11);
        a20 = fmaf(p2, x0, a20); a21 = fmaf(p2, x1, a21);
        a30 = fmaf(p3, x0, a31 == a31 ? a30 : a30); a31 = fmaf(p3, x1, a31);
    }
    unsigned* obase = (unsigned*)(xagg + (size_t)n * 512 + lane * 2);
    obase[0]   = packbf2(a00 * i0, a01 * i0);
    obase[64]  = packbf2(a10 * i1, a11 * i1);
    obase[128] = packbf2(a20 * i2, a21 * i2);
    obase[192] = packbf2(a30 * i3, a31 * i3);
}

// -------- gemm_agg: out1[n, h*128+c'] = xagg[n,h,:] @ W1[:, h*128+c'] ------------
__global__ __launch_bounds__(256) void gemm_agg(const unsigned short* __restrict__ A,
                                                const unsigned short* __restrict__ Bp,
                                                unsigned short* __restrict__ C,
                                                float* __restrict__ stats, int M) {
    constexpr int KT = 4;            // K = 128
    __shared__ float sred[128];
    __shared__ float qred[128];
    if (threadIdx.x < 128) { sred[threadIdx.x] = 0.f; qred[threadIdx.x] = 0.f; }
    __syncthreads();
    int wave = threadIdx.x >> 6, lane = threadIdx.x & 63;
    int hh = blockIdx.y;
    int row0 = (blockIdx.x * 4 + wave) * 16;
    bool act = row0 < M;
    int rowc = act ? row0 : 0;
    int r = lane & 15, quad = lane >> 4;
    short8 af[KT];
    const unsigned short* arow = A + (size_t)(rowc + r) * 512 + hh * CONVD + quad * 8;
#pragma unroll
    for (int kt = 0; kt < KT; kt++) af[kt] = *(const short8*)(arow + kt * 32);
#pragma unroll
    for (int nt = 0; nt < 8; nt++) {
        floatx4 acc = {0.f, 0.f, 0.f, 0.f};
        const unsigned short* bbase = Bp + (((size_t)(hh * 8 + nt) * KT) << 9) + lane * 8;
#pragma unroll
        for (int kt = 0; kt < KT; kt++) {
            short8 bf = *(const short8*)(bbase + ((size_t)kt << 9));
            acc = __builtin_amdgcn_mfma_f32_16x16x32_bf16(af[kt], bf, acc, 0, 0, 0);
        }
        int col = (hh * 8 + nt) * 16 + r;
        unsigned short* cbase = C + (size_t)(rowc + quad * 4) * 512 + col;
        float ls = 0.f, lq = 0.f;
#pragma unroll
        for (int reg = 0; reg < 4; reg++) {
            float v = acc[reg];
            if (act) cbase[(size_t)reg * 512] = f2bf(v);
            ls += v;
            lq = fmaf(v, v, lq);
        }
        if (!act) { ls = 0.f; lq = 0.f; }
        ls += __shfl_xor(ls, 16); ls += __shfl_xor(ls, 32);
        lq += __shfl_xor(lq, 16); lq += __shfl_xor(lq, 32);
        if (quad == 0) {
            atomicAdd(&sred[nt * 16 + r], ls);
            atomicAdd(&qred[nt * 16 + r], lq);
        }
    }
    __syncthreads();
    if (threadIdx.x < 128) {
        int col = hh * CONVD + threadIdx.x;
        atomicAdd(&stats[col], sred[threadIdx.x]);
        atomicAdd(&stats[512 + col], qred[threadIdx.x]);
    }
}

// ---- GEMM2: BN-finalize in LDS + BN on A-load + fused alpha; N split 4-way ------
__global__ __launch_bounds__(256) void gemm2_bn_alpha(const unsigned short* __restrict__ A,
                                                      const unsigned short* __restrict__ Bp,
                                                      const float* __restrict__ stats,
                                                      const float* __restrict__ gamma,
                                                      const float* __restrict__ beta,
                                                      const float* __restrict__ a_s,
                                                      const float* __restrict__ a_d,
                                                      unsigned short* __restrict__ C,
                                                      float* __restrict__ as_out,
                                                      float* __restrict__ ad_out, int M) {
    constexpr int K = 512;
    constexpr int Nn = CONVD;         // 128
    constexpr int KT = K / 32;        // 16
    __shared__ float Ssm[512];
    __shared__ float Tsm[512];
    for (int c = threadIdx.x; c < 512; c += 256) {
        float inv_n = 1.f / (float)NN;
        float mu = stats[c] * inv_n;
        float var = stats[512 + c] * inv_n - mu * mu;
        float s = gamma[c] * rsqrtf(var + EPS_BN);
        Ssm[c] = s;
        Tsm[c] = fmaf(-mu, s, beta[c]);
    }
    __syncthreads();
    int wave = threadIdx.x >> 6, lane = threadIdx.x & 63;
    int row0 = (blockIdx.x * 4 + wave) * 16;
    if (row0 >= M) return;
    int r = lane & 15, quad = lane >> 4;
    int nt0 = blockIdx.y * 2;
    short8 af[KT];
    const unsigned short* arow = A + (size_t)(row0 + r) * K + quad * 8;
#pragma unroll
    for (int kt = 0; kt < KT; kt++) {
        short8 raw = *(const short8*)(arow + kt * 32);
        int k = kt * 32 + quad * 8;
        short8 o;
#pragma unroll
        for (int i = 0; i < 8; i++) {
            float v = fmaf(bf2f((unsigned short)raw[i]), Ssm[k + i], Tsm[k + i]);
            o[i] = (short)f2bf(v > 0.f ? v : 0.f);
        }
        af[kt] = o;
    }
    float asp[4] = {}, adp[4] = {};
#pragma unroll
    for (int nt2 = 0; nt2 < 2; nt2++) {
        int nt = nt0 + nt2;
        floatx4 acc = {0.f, 0.f, 0.f, 0.f};
        const unsigned short* bbase = Bp + (((size_t)nt * KT) << 9) + lane * 8;
#pragma unroll
        for (int kt = 0; kt < KT; kt++) {
            short8 bf = *(const short8*)(bbase + ((size_t)kt << 9));
            acc = __builtin_amdgcn_mfma_f32_16x16x32_bf16(af[kt], bf, acc, 0, 0, 0);
        }
        int col = nt * 16 + r;
        unsigned short* cbase = C + (size_t)(row0 + quad * 4) * Nn + col;
        float sv = a_s[col];
        float dv = a_d[col];
#pragma unroll
        for (int reg = 0; reg < 4; reg++) {
            cbase[(size_t)reg * Nn] = f2bf(acc[reg]);
            asp[reg] = fmaf(acc[reg], sv, asp[reg]);
            adp[reg] = fmaf(acc[reg], dv, adp[reg]);
        }
    }
#pragma unroll
    for (int msk = 1; msk < 16; msk <<= 1) {
#pragma unroll
        for (int reg = 0; reg < 4; reg++) {
            asp[reg] += __shfl_xor(asp[reg], msk);
            adp[reg] += __shfl_xor(adp[reg], msk);
        }
    }
    if (r < 4) {
        int row = row0 + quad * 4 + r;
        atomicAdd(&as_out[row], asp[r]);
        atomicAdd(&ad_out[row], adp[r]);
    }
}

// -------- fused softmax + aggregation, H=1 (one wave per node), LDS + 8-wide -----
__global__ __launch_bounds__(256) void attn_aggr1(const int* __restrict__ rowptr,
                                                  const int* __restrict__ esrc,
                                                  const float* __restrict__ as,
                                                  const float* __restrict__ ad,
                                                  const unsigned short* __restrict__ h,
                                                  float* __restrict__ out) {
    __shared__ float sp[4][64];
    __shared__ int ssrc[4][64];
    int lane = threadIdx.x & 63;
    int wv = threadIdx.x >> 6;
    int n = blockIdx.x * 4 + wv;
    int beg = rowptr[n], end = rowptr[n + 1];
    int deg = end - beg;
    float adn = ad[n];
    float m, sum;
    if (deg <= 64) {
        bool valid = lane < deg;
        int s = esrc[beg + (valid ? lane : 0)];
        float l = valid ? leaky(as[s] + adn) : -INFINITY;
        m = l;
#pragma unroll
        for (int o = 32; o > 0; o >>= 1) m = fmaxf(m, __shfl_xor(m, o));
        float e = valid ? __expf(l - m) : 0.f;
        sum = e;
#pragma unroll
        for (int o = 32; o > 0; o >>= 1) sum += __shfl_xor(sum, o);
        sp[wv][lane] = e;
        ssrc[wv][lane] = s;
    } else {
        m = -INFINITY;
        for (int j = beg + lane; j < end; j += 64)
            m = fmaxf(m, leaky(as[esrc[j]] + adn));
#pragma unroll
        for (int o = 32; o > 0; o >>= 1) m = fmaxf(m, __shfl_xor(m, o));
        sum = 0.f;
        for (int j = beg + lane; j < end; j += 64) {
            int s = esrc[j];
            float e = __expf(leaky(as[s] + adn) - m);
            if (j - beg < 64) { sp[wv][lane] = e; ssrc[wv][lane] = s; }
            sum += e;
        }
#pragma unroll
        for (int o = 32; o > 0; o >>= 1) sum += __shfl_xor(sum, o);
    }
    __syncthreads();
    float inv = 1.f / (sum + 1e-16f);
    float a0 = 0.f, a1 = 0.f;
    const unsigned short* hrow = h + lane * 2;
    int cap = deg < 64 ? deg : 64;
    int jj = 0;
    for (; jj + 7 < cap; jj += 8) {
        int sv[8];
#pragma unroll
        for (int u = 0; u < 8; u++) sv[u] = ssrc[wv][jj + u];
        unsigned xv[8];
#pragma unroll
        for (int u = 0; u < 8; u++) xv[u] = *(const unsigned*)(hrow + (size_t)sv[u] * CONVD);
        float pv[8];
#pragma unroll
        for (int u = 0; u < 8; u++) pv[u] = sp[wv][jj + u];
#pragma unroll
        for (int u = 0; u < 8; u++) {
            a0 = fmaf(pv[u], bf2f((unsigned short)(xv[u] & 0xffffu)), a0);
            a1 = fmaf(pv[u], bf2f((unsigned short)(xv[u] >> 16)), a1);
        }
    }
    for (; jj < cap; jj++) {
        int s = ssrc[wv][jj];
        float p = sp[wv][jj];
        unsigned xv = *(const unsigned*)(hrow + (size_t)s * CONVD);
        a0 = fmaf(p, bf2f((unsigned short)(xv & 0xffffu)), a0);
        a1 = fmaf(p, bf2f((unsigned short)(xv >> 16)), a1);
    }
    for (int j2 = 64; j2 < deg; j2++) {
        int s = esrc[beg + j2];
        float p = __expf(leaky(as[s] + adn) - m);
        unsigned xv = *(const unsigned*)(hrow + (size_t)s * CONVD);
        a0 = fmaf(p, bf2f((unsigned short)(xv & 0xffffu)), a0);
        a1 = fmaf(p, bf2f((unsigned short)(xv >> 16)), a1);
    }
    *(float2*)(out + (size_t)n * CONVD + lane * 2) = make_float2(a0 * inv, a1 * inv);
}

// ---------------- BN stats (f32 input) ----------------
__global__ void bn_stats_f32(const float* __restrict__ x, const float* __restrict__ bias,
                             float* __restrict__ stats, int Nn, int C) {
    const int ROWS = 64;
    int r0 = blockIdx.x * ROWS;
    int rend = min(r0 + ROWS, Nn);
    for (int c = threadIdx.x; c < C; c += blockDim.x) {
        float b = bias[c];
        float s1 = 0.f, s2 = 0.f;
        for (int r = r0; r < rend; r++) {
            float v = x[(size_t)r * C + c] + b;
            s1 += v;
            s2 = fmaf(v, v, s2);
        }
        atomicAdd(&stats[c], s1);
        atomicAdd(&stats[C + c], s2);
    }
}

// ---------------- BN apply + ReLU + pool (layer 2, fused) ------------------------
__global__ void bn_apply_pool(const float* __restrict__ x, const float* __restrict__ bias,
                              const float* __restrict__ stats,
                              const float* __restrict__ gamma, const float* __restrict__ beta,
                              const int* __restrict__ batch, float* __restrict__ z,
                              int Nn, int C) {
    int idx = blockIdx.x * blockDim.x + threadIdx.x;
    if (idx >= Nn * C) return;
    int c = idx % C;
    int n = idx / C;
    float inv_n = 1.f / (float)Nn;
    float mu = stats[c] * inv_n;
    float var = stats[C + c] * inv_n - mu * mu;
    float v = (x[idx] + bias[c] - mu) * rsqrtf(var + EPS_BN);
    v = fmaf(gamma[c], v, beta[c]);
    v = v > 0.f ? v : 0.f;
    atomicAdd(&z[batch[n] * C + c], v);
}

// ---- fused MLP head: one block per graph; coalesced per-output threads with -----
// 8-wide manual load batching (8 independent loads in flight per thread; the
// serial load->fma chain was the 43-50us bottleneck on cold weights)
__global__ __launch_bounds__(320) void mlp_kernel(const float* __restrict__ g,
                           const float* __restrict__ extras,
                           const float* __restrict__ Wm1, const float* __restrict__ bm1,
                           const float* __restrict__ Wm2, const float* __restrict__ bm2,
                           const float* __restrict__ Wm3, const float* __restrict__ bm3,
                           float* __restrict__ out) {
    const int Z0 = CONVD + NXD;   // 137
    const int Z1 = NETD + NXD;    // 265
    const int Z2 = NETD;          // 256
    __shared__ float z[Z0];
    __shared__ float z1[Z1];
    __shared__ float z2[Z2];
    __shared__ float wred[5];
    int gi = blockIdx.x, t = threadIdx.x;
    if (t < CONVD) z[t] = g[gi * CONVD + t];
    else if (t < Z0) z[t] = extras[gi * NXD + (t - CONVD)];
    __syncthreads();
    if (t < Z1) {
        float acc = bm1[t];
        int k = 0;
        for (; k + 8 <= Z0; k += 8) {
            float w[8];
#pragma unroll
            for (int u = 0; u < 8; u++) w[u] = Wm1[(size_t)(k + u) * Z1 + t];
#pragma unroll
            for (int u = 0; u < 8; u++) acc = fmaf(z[k + u], w[u], acc);
        }
        for (; k < Z0; k++) acc = fmaf(z[k], Wm1[(size_t)k * Z1 + t], acc);
        z1[t] = acc > 0.f ? acc : 0.f;
    }
    __syncthreads();
    if (t < Z2) {
        float acc = bm2[t];
        int k = 0;
        for (; k + 8 <= Z1; k += 8) {
            float w[8];
#pragma unroll
            for (int u = 0; u < 8; u++) w[u] = Wm2[(size_t)(k + u) * Z2 + t];
#pragma unroll
            for (int u = 0; u < 8; u++) acc = fmaf(z1[k + u], w[u], acc);
        }
        for (; k < Z1; k++) acc = fmaf(z1[k], Wm2[(size_t)k * Z2 + t], acc);
        z2[t] = acc > 0.f ? acc : 0.f;
    }
    __syncthreads();
    float partial = (t < Z2) ? z2[t] * Wm3[t] : 0.f;
    for (int o = 32; o > 0; o >>= 1) partial += __shfl_down(partial, o);
    int wv = t >> 6, ln = t & 63;
    if (ln == 0) wred[wv] = partial;
    __syncthreads();
    if (t == 0) {
        float s = bm3[0];
        for (int i = 0; i < 5; i++) s += wred[i];
        out[gi] = s;
    }
}

// ---------------- launch ----------------
extern "C" void kernel_launch(void* const* d_in, const int* in_sizes, int n_in,
                              void* d_out, int out_size, void* d_ws, size_t ws_size,
                              hipStream_t stream) {
    const float* x      = (const float*)d_in[0];
    const int*   ei     = (const int*)d_in[1];
    const int*   batch  = (const int*)d_in[2];
    const float* extras = (const float*)d_in[3];
    const float* W1     = (const float*)d_in[4];
    const float* a_s1   = (const float*)d_in[5];
    const float* a_d1   = (const float*)d_in[6];
    const float* b1     = (const float*)d_in[7];
    const float* W2     = (const float*)d_in[8];
    const float* a_s2   = (const float*)d_in[9];
    const float* a_d2   = (const float*)d_in[10];
    const float* b2     = (const float*)d_in[11];
    const float* gamma1 = (const float*)d_in[12];
    const float* beta1  = (const float*)d_in[13];
    const float* gamma2 = (const float*)d_in[14];
    const float* beta2  = (const float*)d_in[15];
    const float* Wm1    = (const float*)d_in[16];
    const float* bm1    = (const float*)d_in[17];
    const float* Wm2    = (const float*)d_in[18];
    const float* bm2    = (const float*)d_in[19];
    const float* Wm3    = (const float*)d_in[20];
    const float* bm3    = (const float*)d_in[21];
    float* out = (float*)d_out;

    const int N = NN, E = EE, EP = EE + NN;

    char* ws = (char*)d_ws;
    size_t off = 0;
    auto alloc = [&](size_t bytes) -> void* {
        void* pp = (void*)(ws + off);
        off += (bytes + 255) & ~(size_t)255;
        return pp;
    };
    // --- zero region (contiguous; one small memset) ---
    int*   deg    = (int*)alloc((size_t)N * 4);
    int*   cursor = (int*)alloc((size_t)N * 4);
    float* stats1 = (float*)alloc(512 * 2 * 4);
    float* stats2 = (float*)alloc(128 * 2 * 4);
    float* zbuf   = (float*)alloc((size_t)GG * CONVD * 4);
    float* as2    = (float*)alloc((size_t)N * 4);      // atomic-accumulated in gemm2
    float* ad2    = (float*)alloc((size_t)N * 4);
    size_t zero_bytes = off;
    // --- scratch (fully overwritten each launch) ---
    int*   rowptr = (int*)alloc((size_t)(N + 1) * 4);
    int*   esrc   = (int*)alloc((size_t)EP * 4);
    unsigned short* xb    = (unsigned short*)alloc((size_t)N * VIN * 2);
    unsigned short* W1p   = (unsigned short*)alloc((size_t)VIN * 512 * 2);
    unsigned short* W2p   = (unsigned short*)alloc((size_t)512 * 128 * 2);
    unsigned short* xagg  = (unsigned short*)alloc((size_t)N * 512 * 2);
    unsigned short* out1b = (unsigned short*)alloc((size_t)N * 512 * 2);
    unsigned short* h2b   = (unsigned short*)alloc((size_t)N * 128 * 2);
    float* out2   = (float*)alloc((size_t)N * 128 * 4);
    float* as1    = (float*)alloc((size_t)N * 4 * 4);
    float* ad1    = (float*)alloc((size_t)N * 4 * 4);
    float* va_s   = (float*)alloc(VIN * 4 * 4);
    float* va_d   = (float*)alloc(VIN * 4 * 4);

    hipMemsetAsync(d_ws, 0, zero_bytes, stream);

    int eb = (EP + 255) / 256;                 // 1642
    int nrow = (N + 63) / 64;                  // 313
    int mblk = (N + 63) / 64;                  // 313
    int nblk4 = N / 4;                         // 5000 (exact)
    int prep_blocks = (N * VIN + 255) / 256 + 256 + 256 + eb + 4;
    int sa_blocks = eb + nblk4;

    // ---- prep (cast + packs + histogram + va) ----
    prep_kernel<<<prep_blocks, 256, 0, stream>>>(x, xb, W1, W1p, W2, W2p, ei, deg,
                                                 a_s1, a_d1, va_s, va_d);

    // ---- CSR build + alpha1 ----
    scan_kernel<<<1, 1024, 0, stream>>>(deg, rowptr, N, EP);
    scatter_alpha<<<sa_blocks, 256, 0, stream>>>(ei, rowptr, cursor, esrc, xb, va_s, va_d, as1, ad1);

    // ---- GAT layer 1 (H=4, concat): x-space aggregation then per-head GEMM ----
    attn_aggr_x4<<<nblk4, 256, 0, stream>>>(rowptr, esrc, as1, ad1, xb, xagg);
    gemm_agg<<<dim3(mblk, 4), 256, 0, stream>>>(xagg, W1p, out1b, stats1, N);

    // ---- GAT layer 2 (H=1): BN finalize folded into GEMM2; N split 4-way ----
    gemm2_bn_alpha<<<dim3(mblk, 4), 256, 0, stream>>>(out1b, W2p, stats1, gamma1, beta1,
                                                      a_s2, a_d2, h2b, as2, ad2, N);
    attn_aggr1<<<nblk4, 256, 0, stream>>>(rowptr, esrc, as2, ad2, h2b, out2);

    // ---- tail: BN2 stats -> apply+pool -> MLP (separate small kernels) ----
    bn_stats_f32<<<nrow, 256, 0, stream>>>(out2, b2, stats2, N, 128);
    bn_apply_pool<<<(N * 128 + 255) / 256, 256, 0, stream>>>(out2, b2, stats2, gamma2, beta2, batch, zbuf, N, 128);
    mlp_kernel<<<GG, 320, 0, stream>>>(zbuf, extras, Wm1, bm1, Wm2, bm2, Wm3, bm3, out);
}